// Round 1
// baseline (301.162 us; speedup 1.0000x reference)
//
#include <hip/hip_runtime.h>

// (1/sqrt(3)) * log2(e): fold softmax scale + exp->exp2 conversion into q.
// Softmax is shift-invariant; scores are O(+-6) so no max-subtraction needed in fp32.
#define QSCALE 0.83294038f

__global__ __launch_bounds__(256, 2) void attn_seg_kernel(
    const float* __restrict__ x,
    const float* __restrict__ Wq, const float* __restrict__ bq,
    const float* __restrict__ Wk, const float* __restrict__ bk,
    const float* __restrict__ Wv, const float* __restrict__ bv,
    const float* __restrict__ Wo, const float* __restrict__ bo,
    float* __restrict__ out, int nb)
{
    // one thread = one batch element; no LDS, no barriers.
    const int b = blockIdx.x * 256 + threadIdx.x;
    if (b >= nb) return;

    const float* __restrict__ xb = x + (size_t)b * 96;   // 16 pos * 6 dim
    float* __restrict__ ob = out + (size_t)b * 96;

    float K[16][6], V[16][6];   // 192 VGPRs, statically indexed everywhere

    // ---- pass A: K,V projections. s is uniform -> weights come from SGPRs (s_load).
    // Load 2 rows (48B) per step so all loads are 16B-aligned dwordx4.
    #pragma unroll
    for (int sp = 0; sp < 8; ++sp) {
        float4 A  = *(const float4*)(xb + sp * 12);
        float4 Bq4 = *(const float4*)(xb + sp * 12 + 4);
        float4 C  = *(const float4*)(xb + sp * 12 + 8);
        float xr[2][6] = {{A.x, A.y, A.z, A.w, Bq4.x, Bq4.y},
                          {Bq4.z, Bq4.w, C.x, C.y, C.z, C.w}};
        #pragma unroll
        for (int h = 0; h < 2; ++h) {
            const int s = sp * 2 + h;
            // SEG = [0, 1*5, 2*3, 3, 4*6] -- compile-time constant per unrolled s
            const int sg = (s == 0) ? 0 : (s < 6) ? 1 : (s < 9) ? 2 : (s == 9) ? 3 : 4;
            const float* wk = Wk + sg * 36;
            const float* wv = Wv + sg * 36;
            #pragma unroll
            for (int j = 0; j < 6; ++j) {
                float accK = bk[sg * 6 + j];
                float accV = bv[sg * 6 + j];
                #pragma unroll
                for (int d = 0; d < 6; ++d) {
                    accK += xr[h][d] * wk[j * 6 + d];
                    accV += xr[h][d] * wv[j * 6 + d];
                }
                K[s][j] = accK;
                V[s][j] = accV;
            }
        }
    }

    // Launder the pointer so q-loop x reloads are NOT CSE'd against pass-A loads
    // (CSE would keep all 96 x values live -> register blowup/spill).
    const float* xq = xb;
    asm volatile("" : "+v"(xq));

    float cx0, cx1, cx2, cx3, cx4, cx5;
    {
        float2 a = *(const float2*)(xq);
        float2 c = *(const float2*)(xq + 2);
        float2 d = *(const float2*)(xq + 4);
        cx0 = a.x; cx1 = a.y; cx2 = c.x; cx3 = c.y; cx4 = d.x; cx5 = d.y;
    }

    #pragma unroll 1
    for (int q = 0; q < 16; ++q) {
        // prefetch next q's x row (L1/L2-warm; hidden under this iteration's math)
        const float* pn = xq + ((q + 1) & 15) * 6;
        float2 na = *(const float2*)(pn);
        float2 nc = *(const float2*)(pn + 2);
        float2 nd = *(const float2*)(pn + 4);

        const int sg = (q == 0) ? 0 : (q < 6) ? 1 : (q < 9) ? 2 : (q == 9) ? 3 : 4;  // uniform
        const float* wq = Wq + sg * 36;
        float qv[6];
        #pragma unroll
        for (int j = 0; j < 6; ++j) {
            float acc = bq[sg * 6 + j];
            acc += cx0 * wq[j * 6 + 0];
            acc += cx1 * wq[j * 6 + 1];
            acc += cx2 * wq[j * 6 + 2];
            acc += cx3 * wq[j * 6 + 3];
            acc += cx4 * wq[j * 6 + 4];
            acc += cx5 * wq[j * 6 + 5];
            qv[j] = acc * QSCALE;
        }

        // fused score -> exp2 -> sum -> PV: e is transient, no score array
        float s0 = 0.f, s1 = 0.f;
        float c0 = 0.f, c1 = 0.f, c2 = 0.f, c3 = 0.f, c4 = 0.f, c5 = 0.f;
        #pragma unroll
        for (int k = 0; k < 16; ++k) {
            float e0 = __builtin_amdgcn_exp2f(qv[0] * K[k][0] + qv[1] * K[k][1] + qv[2] * K[k][2]);
            s0 += e0;
            c0 += e0 * V[k][0]; c1 += e0 * V[k][1]; c2 += e0 * V[k][2];
            float e1 = __builtin_amdgcn_exp2f(qv[3] * K[k][3] + qv[4] * K[k][4] + qv[5] * K[k][5]);
            s1 += e1;
            c3 += e1 * V[k][3]; c4 += e1 * V[k][4]; c5 += e1 * V[k][5];
        }
        const float i0 = __builtin_amdgcn_rcpf(s0);
        const float i1 = __builtin_amdgcn_rcpf(s1);
        c0 *= i0; c1 *= i0; c2 *= i0;
        c3 *= i1; c4 *= i1; c5 *= i1;

        float o_[6];
        #pragma unroll
        for (int i = 0; i < 6; ++i) {
            o_[i] = bo[i] + c0 * Wo[i * 6 + 0] + c1 * Wo[i * 6 + 1] + c2 * Wo[i * 6 + 2]
                          + c3 * Wo[i * 6 + 3] + c4 * Wo[i * 6 + 4] + c5 * Wo[i * 6 + 5];
        }
        float* op = ob + q * 6;
        *(float2*)(op)     = make_float2(o_[0], o_[1]);
        *(float2*)(op + 2) = make_float2(o_[2], o_[3]);
        *(float2*)(op + 4) = make_float2(o_[4], o_[5]);

        cx0 = na.x; cx1 = na.y; cx2 = nc.x; cx3 = nc.y; cx4 = nd.x; cx5 = nd.y;
    }
}

extern "C" void kernel_launch(void* const* d_in, const int* in_sizes, int n_in,
                              void* d_out, int out_size, void* d_ws, size_t ws_size,
                              hipStream_t stream) {
    const float* x  = (const float*)d_in[0];
    const float* Wq = (const float*)d_in[1];
    const float* bq = (const float*)d_in[2];
    const float* Wk = (const float*)d_in[3];
    const float* bk = (const float*)d_in[4];
    const float* Wv = (const float*)d_in[5];
    const float* bv = (const float*)d_in[6];
    const float* Wo = (const float*)d_in[7];
    const float* bo = (const float*)d_in[8];
    float* out = (float*)d_out;

    const int nb   = in_sizes[0] / 96;        // batch elements (16 pos * 6 dim)
    const int grid = (nb + 255) / 256;        // one thread per batch element
    attn_seg_kernel<<<grid, 256, 0, stream>>>(x, Wq, bq, Wk, bk, Wv, bv, Wo, bo, out, nb);
}

// Round 2
// 250.132 us; speedup vs baseline: 1.2040x; 1.2040x over previous
//
#include <hip/hip_runtime.h>

// (1/sqrt(3)) * log2(e): folds softmax scale AND exp->exp2 into q.
// Softmax is shift-invariant and scores are O(+-4) -> no max-subtraction
// needed in fp32 (validated: round-1 kernel used identical math and passed).
#define QSCALE 0.83294038f

// LDS float layout per wave (1056 floats): K at [g*132 + s*8], V at +528.
// Group stride 132 -> groups at disjoint bank quads (132 mod 32 = 4).
#define WAVE_FLOATS 1056
#define VOFF 528
#define GSTRIDE 132

__device__ __forceinline__ void proj6(const float* __restrict__ W5,
                                      const float* __restrict__ b5,
                                      int seg,
                                      float x0, float x1, float x2,
                                      float x3, float x4, float x5,
                                      float r[6])
{
    // W5 + seg*36 floats = seg*144 B -> 16B aligned: 9x dwordx4, L1-hot.
    float w[36];
    const float4* p = (const float4*)(W5 + seg * 36);
    #pragma unroll
    for (int i = 0; i < 9; ++i) {
        float4 v = p[i];
        w[i*4+0] = v.x; w[i*4+1] = v.y; w[i*4+2] = v.z; w[i*4+3] = v.w;
    }
    float bb[6];
    const float2* bp = (const float2*)(b5 + seg * 6);   // seg*24 B: 8B aligned
    #pragma unroll
    for (int i = 0; i < 3; ++i) { float2 v = bp[i]; bb[i*2] = v.x; bb[i*2+1] = v.y; }
    #pragma unroll
    for (int j = 0; j < 6; ++j) {
        r[j] = bb[j] + x0*w[j*6+0] + x1*w[j*6+1] + x2*w[j*6+2]
                     + x3*w[j*6+3] + x4*w[j*6+4] + x5*w[j*6+5];
    }
}

__global__ __launch_bounds__(256) void attn_seg_kernel(
    const float* __restrict__ x,
    const float* __restrict__ Wq, const float* __restrict__ bq,
    const float* __restrict__ Wk, const float* __restrict__ bk,
    const float* __restrict__ Wv, const float* __restrict__ bv,
    const float* __restrict__ Wo, const float* __restrict__ bo,
    float* __restrict__ out, int total)
{
    __shared__ __align__(16) float lds[4 * WAVE_FLOATS];   // 16.5 KB, K/V only
    const int t    = threadIdx.x;
    const int wv_  = t >> 6;      // wave in block
    const int g    = (t >> 4) & 3;// 16-lane group within wave = one batch elem
    const int s    = t & 15;      // sequence position

    // SEG = [0, 1*5, 2*3, 3, 4*6]
    const int seg = (s == 0) ? 0 : (s < 6) ? 1 : (s < 9) ? 2 : (s == 9) ? 3 : 4;

    const int pos = blockIdx.x * 256 + t;   // global flat (b*16+s), coalesced
    const bool valid = pos < total;
    float x0=0.f,x1=0.f,x2=0.f,x3=0.f,x4=0.f,x5=0.f;
    if (valid) {
        const float* xp = x + (size_t)pos * 6;   // contiguous 24B per lane
        float2 a = *(const float2*)(xp);
        float2 b = *(const float2*)(xp + 2);
        float2 c = *(const float2*)(xp + 4);
        x0=a.x; x1=a.y; x2=b.x; x3=b.y; x4=c.x; x5=c.y;
    }

    // ---- Q,K,V projections; weights straight from global (L1-resident) ----
    float q[6], kk[6], vvv[6];
    proj6(Wq, bq, seg, x0,x1,x2,x3,x4,x5, q);
    proj6(Wk, bk, seg, x0,x1,x2,x3,x4,x5, kk);
    proj6(Wv, bv, seg, x0,x1,x2,x3,x4,x5, vvv);
    #pragma unroll
    for (int i = 0; i < 6; ++i) q[i] *= QSCALE;

    // ---- publish K,V for this batch elem (within-wave exchange only) ----
    float* Kd = &lds[wv_ * WAVE_FLOATS + g * GSTRIDE + s * 8];
    *(float4*)Kd       = make_float4(kk[0], kk[1], kk[2], kk[3]);
    *(float2*)(Kd + 4) = make_float2(kk[4], kk[5]);
    float* Vd = Kd + VOFF;
    *(float4*)Vd       = make_float4(vvv[0], vvv[1], vvv[2], vvv[3]);
    *(float2*)(Vd + 4) = make_float2(vvv[4], vvv[5]);

    // Wave-internal visibility: the 16 producer lanes are in THIS wave.
    // No __syncthreads needed; just drain LDS and pin ordering.
    __builtin_amdgcn_wave_barrier();
    asm volatile("s_waitcnt lgkmcnt(0)" ::: "memory");
    __builtin_amdgcn_sched_barrier(0);

    // ---- fused scores -> exp2 -> sum -> PV (e transient, no score array) ----
    const float* Kb = &lds[wv_ * WAVE_FLOATS + g * GSTRIDE];
    const float* Vb = Kb + VOFF;
    float s0 = 0.f, s1 = 0.f;
    float c0=0.f,c1=0.f,c2=0.f,c3=0.f,c4=0.f,c5=0.f;
    #pragma unroll
    for (int k = 0; k < 16; ++k) {
        float4 ka = *(const float4*)(Kb + k * 8);      // broadcast within group
        float2 kb = *(const float2*)(Kb + k * 8 + 4);
        float e0 = __builtin_amdgcn_exp2f(q[0]*ka.x + q[1]*ka.y + q[2]*ka.z);
        float e1 = __builtin_amdgcn_exp2f(q[3]*ka.w + q[4]*kb.x + q[5]*kb.y);
        float4 va = *(const float4*)(Vb + k * 8);
        float2 vb = *(const float2*)(Vb + k * 8 + 4);
        s0 += e0; s1 += e1;
        c0 += e0*va.x; c1 += e0*va.y; c2 += e0*va.z;
        c3 += e1*va.w; c4 += e1*vb.x; c5 += e1*vb.y;
    }
    const float i0 = __builtin_amdgcn_rcpf(s0);
    const float i1 = __builtin_amdgcn_rcpf(s1);
    c0 *= i0; c1 *= i0; c2 *= i0;
    c3 *= i1; c4 *= i1; c5 *= i1;

    // ---- output projection: Wo,bo are wave-uniform -> s_load / SGPR operands
    float o_[6];
    #pragma unroll
    for (int i = 0; i < 6; ++i) {
        o_[i] = bo[i] + c0*Wo[i*6+0] + c1*Wo[i*6+1] + c2*Wo[i*6+2]
                      + c3*Wo[i*6+3] + c4*Wo[i*6+4] + c5*Wo[i*6+5];
    }

    if (valid) {
        float* op = out + (size_t)pos * 6;   // contiguous 24B per lane
        *(float2*)(op)     = make_float2(o_[0], o_[1]);
        *(float2*)(op + 2) = make_float2(o_[2], o_[3]);
        *(float2*)(op + 4) = make_float2(o_[4], o_[5]);
    }
}

extern "C" void kernel_launch(void* const* d_in, const int* in_sizes, int n_in,
                              void* d_out, int out_size, void* d_ws, size_t ws_size,
                              hipStream_t stream) {
    const float* x  = (const float*)d_in[0];
    const float* Wq = (const float*)d_in[1];
    const float* bq = (const float*)d_in[2];
    const float* Wk = (const float*)d_in[3];
    const float* bk = (const float*)d_in[4];
    const float* Wv = (const float*)d_in[5];
    const float* bv = (const float*)d_in[6];
    const float* Wo = (const float*)d_in[7];
    const float* bo = (const float*)d_in[8];
    float* out = (float*)d_out;

    const int total = in_sizes[0] / 6;          // B*16 positions
    const int grid  = (total + 255) / 256;      // 16 batch elems / block
    attn_seg_kernel<<<grid, 256, 0, stream>>>(x, Wq, bq, Wk, bk, Wv, bv, Wo, bo, out, total);
}